// Round 2
// baseline (172.341 us; speedup 1.0000x reference)
//
#include <hip/hip_runtime.h>

// out[n,c,p,y,x] = in1[n,c,y,x] - zpad(in2)[n,c, y+i-3, x+j-3],  p = i*7+j
// N=8, C=32, H=W=112, K=7, pad=3 -> out [8,32,49,112,112] fp32 (629 MB).
//
// R1 restructure: one block per (nc, p) plane -> each block writes ONE
// contiguous 200 KB stream (R0's 49 interleaved 50KB-strided streams per wave
// thrashed DRAM row buffers: 4.86 TB/s vs 6.8 TB/s fill ceiling).
// Block order b = p*256 + nc => XCD = b%8 = nc%8: all 49 p-planes of a given
// nc stay on one XCD; per-XCD input working set = 32 nc * 100 KB = 3.2 MB
// (L2-resident). Nontemporal stores keep the write stream from evicting it.

#define NC_TOT 256        // 8*32
#define HW     112
#define PLANE  12544      // 112*112
#define KK     49

typedef float f4 __attribute__((ext_vector_type(4)));

__global__ __launch_bounds__(448) void sub2_plane_kernel(
    const float* __restrict__ in1,
    const float* __restrict__ in2,
    float* __restrict__ out)
{
    const int b  = blockIdx.x;
    const int nc = b & 255;     // b % 256  (fastest-varying -> XCD = nc%8)
    const int p  = b >> 8;      // 0..48
    const int dy = p / 7 - 3;
    const int dx = p % 7 - 3;

    const float* a_pl = in1 + (size_t)nc * PLANE;
    const float* b_pl = in2 + (size_t)nc * PLANE;
    float*       o_pl = out + ((size_t)nc * KK + p) * PLANE;

    const int tid = threadIdx.x;        // 0..447 (7 waves)
    const int y0  = tid / 28;           // 0..15
    const int x0  = (tid % 28) * 4;     // 0..108

    #pragma unroll
    for (int k = 0; k < 7; ++k) {
        const int y = y0 + k * 16;
        const f4 a = *reinterpret_cast<const f4*>(a_pl + y * HW + x0);

        float w[4] = {0.f, 0.f, 0.f, 0.f};
        const int iy = y + dy;
        if (iy >= 0 && iy < HW) {
            const float* row = b_pl + iy * HW;
            const int xb = x0 + dx;
            #pragma unroll
            for (int m = 0; m < 4; ++m) {
                const int xx = xb + m;
                const int xc = xx < 0 ? 0 : (xx > HW - 1 ? HW - 1 : xx);
                const float v = row[xc];            // clamped addr, always safe
                w[m] = (xx >= 0 && xx < HW) ? v : 0.f;  // mask pad region
            }
        }

        f4 r;
        r.x = a.x - w[0];
        r.y = a.y - w[1];
        r.z = a.z - w[2];
        r.w = a.w - w[3];
        __builtin_nontemporal_store(r, reinterpret_cast<f4*>(o_pl + y * HW + x0));
    }
}

extern "C" void kernel_launch(void* const* d_in, const int* in_sizes, int n_in,
                              void* d_out, int out_size, void* d_ws, size_t ws_size,
                              hipStream_t stream) {
    const float* in1 = (const float*)d_in[0];
    const float* in2 = (const float*)d_in[1];
    float* out = (float*)d_out;

    const int blocks = KK * NC_TOT;   // 12544, b = p*256 + nc
    sub2_plane_kernel<<<blocks, 448, 0, stream>>>(in1, in2, out);
}